// Round 1
// baseline (276.140 us; speedup 1.0000x reference)
//
#include <hip/hip_runtime.h>
#include <hip/hip_fp16.h>
#include <cstdint>
#include <cstddef>

#define BB 4
#define CC 256
#define NN 4096
#define EPS_NORM 2.220446049250313e-16f
#define EPS_MIN 1e-5f

typedef __attribute__((ext_vector_type(8))) short short8;
typedef __attribute__((ext_vector_type(4))) float floatx4;
typedef __attribute__((ext_vector_type(2))) _Float16 half2v;

__device__ __forceinline__ unsigned fmap(float f) {
    unsigned u = __float_as_uint(f);
    return (u & 0x80000000u) ? ~u : (u | 0x80000000u);
}
__device__ __forceinline__ float funmap(unsigned u) {
    return (u & 0x80000000u) ? __uint_as_float(u ^ 0x80000000u) : __uint_as_float(~u);
}
__device__ __forceinline__ unsigned short f2bf(float f) {
    unsigned u = __float_as_uint(f);
    u += 0x7FFFu + ((u >> 16) & 1u);   // RNE
    return (unsigned short)(u >> 16);
}
__device__ __forceinline__ void async_cp16(const void* g, void* l) {
    __builtin_amdgcn_global_load_lds(
        (const __attribute__((address_space(1))) unsigned int*)g,
        (__attribute__((address_space(3))) unsigned int*)l, 16, 0, 0);
}

// ---- K1: per-channel spatial mean of Y (float4) ---------------------------
__global__ void kmean(const float* __restrict__ Y, float* __restrict__ ymean) {
    int bc = blockIdx.x;  // b*CC + c
    const float4* p = (const float4*)(Y + (size_t)bc * NN);
    float s = 0.f;
    for (int k = threadIdx.x; k < NN / 4; k += 256) {
        float4 v = p[k];
        s += (v.x + v.y) + (v.z + v.w);
    }
    __shared__ float red[256];
    red[threadIdx.x] = s; __syncthreads();
    for (int st = 128; st > 0; st >>= 1) {
        if (threadIdx.x < st) red[threadIdx.x] += red[threadIdx.x + st];
        __syncthreads();
    }
    if (threadIdx.x == 0) ymean[bc] = red[0] * (1.0f / NN);
}

// ------- K2: fused norm + normalize + transpose -> bf16 [B,N,C] -------------
__global__ __launch_bounds__(256)
void kfuse(const float* __restrict__ X, const float* __restrict__ Y,
           const float* __restrict__ ymean,
           unsigned short* __restrict__ XnT, unsigned short* __restrict__ YnT) {
    int b = blockIdx.y >> 1, which = blockIdx.y & 1;
    const float* src = which ? Y : X;
    unsigned short* dst = which ? YnT : XnT;
    int n0 = blockIdx.x * 64;
    int tx = threadIdx.x & 63, ty = threadIdx.x >> 6;
    __shared__ float mean_s[CC];
    __shared__ float red[4][64];
    __shared__ float invn[64];
    __shared__ float tile[64][65];
    mean_s[threadIdx.x] = ymean[b * CC + threadIdx.x];
    __syncthreads();
    float vreg[64];
    float s = 0.f;
    #pragma unroll
    for (int k = 0; k < 64; ++k) {
        int c = ty + 4 * k;
        float v = src[(((size_t)b * CC + c) << 12) + n0 + tx] - mean_s[c];
        vreg[k] = v;
        s += v * v;
    }
    red[ty][tx] = s; __syncthreads();
    if (ty == 0) {
        float t = red[0][tx] + red[1][tx] + red[2][tx] + red[3][tx];
        invn[tx] = 1.0f / (sqrtf(t) + EPS_NORM);
    }
    __syncthreads();
    float inv = invn[tx];
    for (int cb = 0; cb < 4; ++cb) {
        if (cb) __syncthreads();
        #pragma unroll
        for (int kk = 0; kk < 16; ++kk) {
            tile[4 * kk + ty][tx] = vreg[cb * 16 + kk] * inv;
        }
        __syncthreads();
        #pragma unroll
        for (int it = 0; it < 16; ++it) {
            int nl = ty + it * 4;
            dst[((size_t)(b * NN + n0 + nl)) * CC + cb * 64 + tx] = f2bf(tile[tx][nl]);
        }
    }
}

// ---------------- init column-max accumulator -------------------------------
__global__ void kinitC(unsigned* __restrict__ colmaxU) {
    colmaxU[blockIdx.x * 256 + threadIdx.x] = 0x007FFFFFu;  // fmap(-inf)
}

// ---- krow: fused row-panel GEMM + full softmax stats, S in registers -------
// Block = 512 thr (8 waves), owns 32 full rows of S (32 x 4096).
// S held as packed fp16 in regs (128 VGPR). B (YnT) streamed via double-
// buffered XOR-swizzled LDS with global_load_lds; A-tile (32x256) in LDS.
__global__ __launch_bounds__(512, 2)
void krow(const unsigned short* __restrict__ XnT, const unsigned short* __restrict__ YnT,
          unsigned* __restrict__ colmaxU) {
    const int tid = threadIdx.x;
    const int lane = tid & 63, wave = tid >> 6;
    const int l15 = lane & 15, quad = lane >> 4;
    // XCD-aware swizzle: batch b owns XCDs {2b, 2b+1} so its 2 MB YnT stays
    // L2-resident (default round-robin would put 4 batches = 8 MB on each XCD).
    const int r8 = blockIdx.x & 7, k8 = blockIdx.x >> 3;
    const int b = r8 >> 1;
    const int ib = (k8 << 1) | (r8 & 1);     // 0..127
    const int i0 = ib * 32;
    const int wn = wave;                      // wave's 32-col j-slice per chunk

    __shared__ unsigned short BsF[2 * 256 * 64];   // 64 KiB double buffer
    __shared__ unsigned short AsF[32 * 256];       // 16 KiB A-tile
    __shared__ float rred[32][8];
    __shared__ float aS[32], gS[32];

    // ---- stage A (32 x 256) once; 3-bit XOR swizzle on 16B chunks ----------
    #pragma unroll
    for (int k = 0; k < 2; ++k) {
        int f = tid + k * 512;                 // 1024 chunk slots
        int row = f >> 5, p5 = f & 31;
        int g = (p5 & 24) | ((p5 ^ row) & 7);  // LDS[row][p5] = G[row][g]
        async_cp16(XnT + ((size_t)b * NN + i0 + row) * CC + g * 8,
                   AsF + (size_t)k * 4096 + wave * 512);
    }

    // ---- B staging setup (proven kgemm pattern, 256 rows/unit) -------------
    const int rl = lane >> 3, pos = lane & 7;
    const int cbx = pos ^ rl;
    const unsigned short* gBl = YnT + ((size_t)b * NN + wave * 32 + rl) * CC + cbx * 8;
    unsigned short* lBw = BsF + wave * 32 * 64;

#define STAGE_B(un) do { \
        const unsigned short* gs_ = gBl + (size_t)((un) >> 2) * 256 * CC + ((un) & 3) * 64; \
        unsigned short* lb_ = lBw + ((un) & 1) * (256 * 64); \
        async_cp16(gs_ + 0 * 8 * CC, lb_ + 0 * 8 * 64); \
        async_cp16(gs_ + 1 * 8 * CC, lb_ + 1 * 8 * 64); \
        async_cp16(gs_ + 2 * 8 * CC, lb_ + 2 * 8 * 64); \
        async_cp16(gs_ + 3 * 8 * CC, lb_ + 3 * 8 * 64); \
    } while (0)

    STAGE_B(0);

    floatx4 acc[2][2];
    #pragma unroll
    for (int ms = 0; ms < 2; ++ms)
        #pragma unroll
        for (int ns = 0; ns < 2; ++ns) acc[ms][ns] = (floatx4){0.f, 0.f, 0.f, 0.f};
    float rm[2][4];
    #pragma unroll
    for (int ms = 0; ms < 2; ++ms)
        #pragma unroll
        for (int r = 0; r < 4; ++r) rm[ms][r] = -1e30f;
    half2v S_reg[16][8];    // [jc][ms*4+r] = (s(ns=0), s(ns=1)) — all static idx

    // ---- main pipeline: 64 units = 16 j-chunks x 4 k-steps -----------------
    #pragma unroll
    for (int u = 0; u < 64; ++u) {
        const int jc = u >> 2, kc = u & 3;
        __syncthreads();                        // drains stage(u) (vmcnt) + reads(u-1)
        if (u + 1 < 64) STAGE_B(u + 1);         // issue before compute (T3 lesson)
        const unsigned short* Bb = BsF + (u & 1) * (256 * 64);
        #pragma unroll
        for (int kkh = 0; kkh < 2; ++kkh) {
            const int swb = ((((kkh << 2) + quad) ^ (l15 & 7)) << 3);
            short8 b0 = *(const short8*)&Bb[(wn * 32 + l15) * 64 + swb];
            short8 b1 = *(const short8*)&Bb[(wn * 32 + 16 + l15) * 64 + swb];
            const int ga = ((kc * 2 + kkh) << 2) + quad;
            const int pa = ((ga & 24) | ((ga ^ l15) & 7)) << 3;
            short8 a0 = *(const short8*)&AsF[l15 * 256 + pa];
            short8 a1 = *(const short8*)&AsF[(16 + l15) * 256 + pa];
            acc[0][0] = __builtin_amdgcn_mfma_f32_16x16x32_bf16(a0, b0, acc[0][0], 0, 0, 0);
            acc[0][1] = __builtin_amdgcn_mfma_f32_16x16x32_bf16(a0, b1, acc[0][1], 0, 0, 0);
            acc[1][0] = __builtin_amdgcn_mfma_f32_16x16x32_bf16(a1, b0, acc[1][0], 0, 0, 0);
            acc[1][1] = __builtin_amdgcn_mfma_f32_16x16x32_bf16(a1, b1, acc[1][1], 0, 0, 0);
        }
        if (kc == 3) {   // j-chunk done: rowmax from fp32, pack S to fp16 regs
            #pragma unroll
            for (int ms = 0; ms < 2; ++ms)
                #pragma unroll
                for (int r = 0; r < 4; ++r) {
                    float v0 = acc[ms][0][r], v1 = acc[ms][1][r];
                    rm[ms][r] = fmaxf(rm[ms][r], fmaxf(v0, v1));
                    S_reg[jc][ms * 4 + r] = (half2v){(_Float16)v0, (_Float16)v1};
                }
            #pragma unroll
            for (int ms = 0; ms < 2; ++ms)
                #pragma unroll
                for (int ns = 0; ns < 2; ++ns) acc[ms][ns] = (floatx4){0.f, 0.f, 0.f, 0.f};
        }
    }
#undef STAGE_B

    // ---- phase 2: rowmax -> alpha ------------------------------------------
    #pragma unroll
    for (int ms = 0; ms < 2; ++ms)
        #pragma unroll
        for (int r = 0; r < 4; ++r) {
            float m = rm[ms][r];
            m = fmaxf(m, __shfl_xor(m, 1)); m = fmaxf(m, __shfl_xor(m, 2));
            m = fmaxf(m, __shfl_xor(m, 4)); m = fmaxf(m, __shfl_xor(m, 8));
            if (l15 == 0) rred[ms * 16 + quad * 4 + r][wn] = m;
        }
    __syncthreads();
    if (tid < 32) {
        float mx = rred[tid][0];
        #pragma unroll
        for (int w = 1; w < 8; ++w) mx = fmaxf(mx, rred[tid][w]);
        aS[tid] = 10.0f / ((1.0f - mx) + EPS_MIN);
    }
    __syncthreads();

    // ---- phase 3: rowsum of exp -> gamma -----------------------------------
    float a_[2][4];
    #pragma unroll
    for (int ms = 0; ms < 2; ++ms)
        #pragma unroll
        for (int r = 0; r < 4; ++r) a_[ms][r] = aS[ms * 16 + quad * 4 + r];
    float sum_[2][4];
    #pragma unroll
    for (int ms = 0; ms < 2; ++ms)
        #pragma unroll
        for (int r = 0; r < 4; ++r) sum_[ms][r] = 0.f;
    #pragma unroll
    for (int jc = 0; jc < 16; ++jc)
        #pragma unroll
        for (int ms = 0; ms < 2; ++ms)
            #pragma unroll
            for (int r = 0; r < 4; ++r) {
                half2v h = S_reg[jc][ms * 4 + r];
                float a = a_[ms][r], c = 10.0f - a;
                sum_[ms][r] += __expf(fmaf(a, (float)h[0], c))
                             + __expf(fmaf(a, (float)h[1], c));
            }
    #pragma unroll
    for (int ms = 0; ms < 2; ++ms)
        #pragma unroll
        for (int r = 0; r < 4; ++r) {
            float s = sum_[ms][r];
            s += __shfl_xor(s, 1); s += __shfl_xor(s, 2);
            s += __shfl_xor(s, 4); s += __shfl_xor(s, 8);
            if (l15 == 0) rred[ms * 16 + quad * 4 + r][wn] = s;
        }
    __syncthreads();
    if (tid < 32) {
        float t = 0.f;
        #pragma unroll
        for (int w = 0; w < 8; ++w) t += rred[tid][w];
        gS[tid] = (10.0f - logf(t)) - aS[tid];     // t_ij = g + a*s
    }
    __syncthreads();

    // ---- phase 4: column max over the block's 32 rows -> atomicMax ---------
    float g_[2][4];
    #pragma unroll
    for (int ms = 0; ms < 2; ++ms)
        #pragma unroll
        for (int r = 0; r < 4; ++r) g_[ms][r] = gS[ms * 16 + quad * 4 + r];
    const size_t bNN = (size_t)b * NN;
    #pragma unroll
    for (int jc = 0; jc < 16; ++jc) {
        float c0 = -1e30f, c1 = -1e30f;
        #pragma unroll
        for (int ms = 0; ms < 2; ++ms)
            #pragma unroll
            for (int r = 0; r < 4; ++r) {
                half2v h = S_reg[jc][ms * 4 + r];
                c0 = fmaxf(c0, fmaf(a_[ms][r], (float)h[0], g_[ms][r]));
                c1 = fmaxf(c1, fmaf(a_[ms][r], (float)h[1], g_[ms][r]));
            }
        c0 = fmaxf(c0, __shfl_xor(c0, 16)); c0 = fmaxf(c0, __shfl_xor(c0, 32));
        c1 = fmaxf(c1, __shfl_xor(c1, 16)); c1 = fmaxf(c1, __shfl_xor(c1, 32));
        if (quad == 0) {
            atomicMax(&colmaxU[bNN + jc * 256 + wn * 32 + l15], fmap(c0));
            atomicMax(&colmaxU[bNN + jc * 256 + wn * 32 + 16 + l15], fmap(c1));
        }
    }
}

// ---- final: out[b] = log(N) - log(sum_j exp(colmax_j)) ---------------------
__global__ void kfinalR(const unsigned* __restrict__ colmaxU, float* __restrict__ out) {
    int b = blockIdx.x;
    float s = 0.f;
    for (int j = threadIdx.x; j < NN; j += 256) s += __expf(funmap(colmaxU[b * NN + j]));
    __shared__ float red[256];
    red[threadIdx.x] = s; __syncthreads();
    for (int st = 128; st > 0; st >>= 1) {
        if (threadIdx.x < st) red[threadIdx.x] += red[threadIdx.x + st];
        __syncthreads();
    }
    if (threadIdx.x == 0) out[b] = logf((float)NN) - logf(red[0]);
}

extern "C" void kernel_launch(void* const* d_in, const int* in_sizes, int n_in,
                              void* d_out, int out_size, void* d_ws, size_t ws_size,
                              hipStream_t stream) {
    const float* X = (const float*)d_in[0];
    const float* Y = (const float*)d_in[1];
    float* out = (float*)d_out;

    char* w = (char*)d_ws;
    float* ymean        = (float*)(w + 0);          //   4 KiB
    unsigned* colmaxU   = (unsigned*)(w + 4096);    //  64 KiB
    unsigned short* XnT = (unsigned short*)(w + 69632);    // 8 MiB
    unsigned short* YnT = (unsigned short*)(w + 8458240);  // 8 MiB -> total ~16.1 MiB

    kmean<<<dim3(BB * CC), 256, 0, stream>>>(Y, ymean);
    kfuse<<<dim3(NN / 64, BB * 2), 256, 0, stream>>>(X, Y, ymean, XnT, YnT);
    kinitC<<<dim3(BB * NN / 256), 256, 0, stream>>>(colmaxU);
    krow<<<dim3(BB * NN / 32), 512, 0, stream>>>(XnT, YnT, colmaxU);
    kfinalR<<<dim3(BB), 256, 0, stream>>>(colmaxU, out);
}